// Round 1
// baseline (307.554 us; speedup 1.0000x reference)
//
#include <hip/hip_runtime.h>

typedef __attribute__((ext_vector_type(8))) _Float16 h8;
typedef __attribute__((ext_vector_type(4))) float f4;

#define QKSCALE 0.18033688011112042f  // 2^-3 * log2(e): fold softmax scale + exp2 conversion into Q

// ---------------- cast x (fp32 -> f16) ----------------
__global__ __launch_bounds__(256) void cast_f16_kernel(const float* __restrict__ in,
                                                       _Float16* __restrict__ out, int n) {
  int i = (blockIdx.x * 256 + threadIdx.x) * 8;
  if (i >= n) return;
  const float4* p = (const float4*)(in + i);
  float4 a = p[0], b = p[1];
  h8 v;
  v[0] = (_Float16)a.x; v[1] = (_Float16)a.y; v[2] = (_Float16)a.z; v[3] = (_Float16)a.w;
  v[4] = (_Float16)b.x; v[5] = (_Float16)b.y; v[6] = (_Float16)b.z; v[7] = (_Float16)b.w;
  *(h8*)(out + i) = v;
}

// ---------------- transpose-cast W [K][N] fp32 -> Wt [N][K] f16 ----------------
__global__ __launch_bounds__(256) void transp_cast_kernel(const float* __restrict__ W,
                                                          _Float16* __restrict__ Wt, int K, int N) {
  __shared__ _Float16 tile[64][72];
  int k0 = blockIdx.y * 64, n0 = blockIdx.x * 64;
  int t = threadIdx.x;
#pragma unroll
  for (int i = 0; i < 16; ++i) {
    int idx = i * 256 + t;
    int kr = idx >> 6, nc = idx & 63;
    tile[kr][nc] = (_Float16)W[(size_t)(k0 + kr) * N + n0 + nc];
  }
  __syncthreads();
#pragma unroll
  for (int i = 0; i < 2; ++i) {
    int idx = i * 256 + t;
    int nr = idx >> 3, kc = (idx & 7) * 8;
    h8 v;
#pragma unroll
    for (int j = 0; j < 8; ++j) v[j] = tile[kc + j][nr];
    *(h8*)&Wt[(size_t)(n0 + nr) * K + k0 + kc] = v;
  }
}

// ---------------- GEMM: C[M,N] = A[M,K] * Bt[N,K]^T (+bias), f16 MFMA ----------------
// MODE 0: outF fp32 row-major.  MODE 1: QKV scatter -> Q[B,H,T,D]*QKSCALE, K[B,H,T,D], V^T[B,H,D,T]
template <int MODE>
__global__ __launch_bounds__(256) void gemm_f16(const _Float16* __restrict__ A,
                                                const _Float16* __restrict__ Bt,
                                                const float* __restrict__ bias,
                                                float* __restrict__ outF,
                                                _Float16* __restrict__ oQ,
                                                _Float16* __restrict__ oK,
                                                _Float16* __restrict__ oV,
                                                int M, int N, int K) {
  __shared__ _Float16 As[128 * 64];
  __shared__ _Float16 Bs[128 * 64];
  const int m0 = blockIdx.y * 128, n0 = blockIdx.x * 128;
  const int tid = threadIdx.x;
  const int wave = tid >> 6, lane = tid & 63;
  const int wr = (wave >> 1) * 64, wc = (wave & 1) * 64;
  const int lrow = lane & 15, g = lane >> 4;
  f4 acc[4][4];
  const f4 z4 = {0.f, 0.f, 0.f, 0.f};
#pragma unroll
  for (int m = 0; m < 4; ++m)
#pragma unroll
    for (int n = 0; n < 4; ++n) acc[m][n] = z4;

  for (int k0 = 0; k0 < K; k0 += 64) {
    // stage A/B tiles [128 rows][64 k] with XOR chunk swizzle (chunk = 16B):
    // LDS (row, c) holds global chunk (c ^ (row&7)) -> frag reads spread across banks
#pragma unroll
    for (int i = 0; i < 4; ++i) {
      int L = i * 256 + tid;
      int row = L >> 3, c = L & 7;
      int cs = (c ^ (row & 7)) * 8;
      *(h8*)&As[row * 64 + c * 8] = *(const h8*)&A[(size_t)(m0 + row) * K + k0 + cs];
      *(h8*)&Bs[row * 64 + c * 8] = *(const h8*)&Bt[(size_t)(n0 + row) * K + k0 + cs];
    }
    __syncthreads();
#pragma unroll
    for (int ss = 0; ss < 2; ++ss) {
      h8 af[4], bf[4];
#pragma unroll
      for (int m = 0; m < 4; ++m) {
        int row = wr + m * 16 + lrow;
        af[m] = *(const h8*)&As[row * 64 + (((ss * 4 + g) ^ (row & 7)) * 8)];
      }
#pragma unroll
      for (int n = 0; n < 4; ++n) {
        int row = wc + n * 16 + lrow;
        bf[n] = *(const h8*)&Bs[row * 64 + (((ss * 4 + g) ^ (row & 7)) * 8)];
      }
#pragma unroll
      for (int m = 0; m < 4; ++m)
#pragma unroll
        for (int n = 0; n < 4; ++n)
          acc[m][n] = __builtin_amdgcn_mfma_f32_16x16x32_f16(af[m], bf[n], acc[m][n], 0, 0, 0);
    }
    __syncthreads();
  }

  // epilogue; C/D layout: col = lane&15, row = (lane>>4)*4 + r  [m89]
#pragma unroll
  for (int n = 0; n < 4; ++n) {
    const int gcol = n0 + wc + n * 16 + lrow;
    const float bv = bias ? bias[gcol] : 0.f;
#pragma unroll
    for (int m = 0; m < 4; ++m) {
#pragma unroll
      for (int r = 0; r < 4; ++r) {
        const int grow = m0 + wr + m * 16 + g * 4 + r;
        float v = acc[m][n][r] + bv;
        if (MODE == 0) {
          outF[(size_t)grow * N + gcol] = v;
        } else {
          int part = gcol >> 10;
          int c1 = gcol & 1023;
          int hh = c1 >> 6, d = c1 & 63;
          int b = grow >> 11, t = grow & 2047;
          int bh = b * 16 + hh;
          if (part == 0)
            oQ[((size_t)bh * 2048 + t) * 64 + d] = (_Float16)(v * QKSCALE);
          else if (part == 1)
            oK[((size_t)bh * 2048 + t) * 64 + d] = (_Float16)v;
          else
            oV[((size_t)bh * 64 + d) * 2048 + t] = (_Float16)v;
        }
      }
    }
  }
}

// ---------------- flash attention (causal), 4 waves x 16 q-rows, KV tile 64 ----------------
__global__ __launch_bounds__(256) void attn_kernel(const _Float16* __restrict__ Qg,
                                                   const _Float16* __restrict__ Kg,
                                                   const _Float16* __restrict__ Vtg,
                                                   _Float16* __restrict__ Og) {
  __shared__ _Float16 plds[4][16][72];  // wave-private P slab, padded rows (144B)
  const int bid = blockIdx.x;
  const int bh = bid >> 5, qt = bid & 31;
  const int q0 = qt * 64;
  const int wave = threadIdx.x >> 6, lane = threadIdx.x & 63;
  const int lrow = lane & 15, g = lane >> 4;
  const int b = bh >> 4, h = bh & 15;
  const _Float16* Q = Qg + (size_t)bh * 2048 * 64;
  const _Float16* K = Kg + (size_t)bh * 2048 * 64;
  const _Float16* Vt = Vtg + (size_t)bh * 64 * 2048;
  const int qw = q0 + wave * 16;

  h8 aq[2];
  aq[0] = *(const h8*)&Q[(qw + lrow) * 64 + g * 8];
  aq[1] = *(const h8*)&Q[(qw + lrow) * 64 + 32 + g * 8];

  const f4 z4 = {0.f, 0.f, 0.f, 0.f};
  f4 o[4];
#pragma unroll
  for (int dt = 0; dt < 4; ++dt) o[dt] = z4;
  float mrow[4] = {-1e30f, -1e30f, -1e30f, -1e30f};
  float lsum[4] = {0.f, 0.f, 0.f, 0.f};
  _Float16(*pw)[72] = plds[wave];

  for (int it = 0; it <= qt; ++it) {
    const int kv0 = it * 64;
    f4 s[4];
#pragma unroll
    for (int ct = 0; ct < 4; ++ct) s[ct] = z4;
#pragma unroll
    for (int ss = 0; ss < 2; ++ss) {
#pragma unroll
      for (int ct = 0; ct < 4; ++ct) {
        h8 bk = *(const h8*)&K[(kv0 + ct * 16 + lrow) * 64 + ss * 32 + g * 8];
        s[ct] = __builtin_amdgcn_mfma_f32_16x16x32_f16(aq[ss], bk, s[ct], 0, 0, 0);
      }
    }
    if (kv0 == q0) {  // only the diagonal tile needs masking
#pragma unroll
      for (int ct = 0; ct < 4; ++ct)
#pragma unroll
        for (int r = 0; r < 4; ++r)
          if (kv0 + ct * 16 + lrow > qw + g * 4 + r) s[ct][r] = -1e30f;
    }
    // online softmax (exp2 domain; scale folded into Q). Row r lives in 16-lane group g.
#pragma unroll
    for (int r = 0; r < 4; ++r) {
      float pm = fmaxf(fmaxf(s[0][r], s[1][r]), fmaxf(s[2][r], s[3][r]));
      pm = fmaxf(pm, __shfl_xor(pm, 1));
      pm = fmaxf(pm, __shfl_xor(pm, 2));
      pm = fmaxf(pm, __shfl_xor(pm, 4));
      pm = fmaxf(pm, __shfl_xor(pm, 8));
      float mn = fmaxf(mrow[r], pm);
      float fr = __builtin_amdgcn_exp2f(mrow[r] - mn);
      mrow[r] = mn;
      float ps = 0.f;
#pragma unroll
      for (int ct = 0; ct < 4; ++ct) {
        float p = __builtin_amdgcn_exp2f(s[ct][r] - mn);
        s[ct][r] = p;
        ps += p;
      }
      ps += __shfl_xor(ps, 1);
      ps += __shfl_xor(ps, 2);
      ps += __shfl_xor(ps, 4);
      ps += __shfl_xor(ps, 8);
      lsum[r] = lsum[r] * fr + ps;
#pragma unroll
      for (int dt = 0; dt < 4; ++dt) o[dt][r] *= fr;
    }
    // P (C/D layout) -> LDS -> A-frag layout (wave-private, no barrier needed)
#pragma unroll
    for (int ct = 0; ct < 4; ++ct)
#pragma unroll
      for (int r = 0; r < 4; ++r) pw[g * 4 + r][ct * 16 + lrow] = (_Float16)s[ct][r];
    h8 ap[2];
    ap[0] = *(const h8*)&pw[lrow][g * 8];
    ap[1] = *(const h8*)&pw[lrow][32 + g * 8];
#pragma unroll
    for (int ss = 0; ss < 2; ++ss) {
#pragma unroll
      for (int dt = 0; dt < 4; ++dt) {
        h8 bv = *(const h8*)&Vt[(size_t)(dt * 16 + lrow) * 2048 + kv0 + ss * 32 + g * 8];
        o[dt] = __builtin_amdgcn_mfma_f32_16x16x32_f16(ap[ss], bv, o[dt], 0, 0, 0);
      }
    }
  }
  // normalize + write O as f16 [B,T,C]
#pragma unroll
  for (int r = 0; r < 4; ++r) {
    float inv = 1.f / lsum[r];
    const int trow = qw + g * 4 + r;
#pragma unroll
    for (int dt = 0; dt < 4; ++dt) {
      Og[((size_t)b * 2048 + trow) * 1024 + h * 64 + dt * 16 + lrow] = (_Float16)(o[dt][r] * inv);
    }
  }
}

// ---------------- launch ----------------
extern "C" void kernel_launch(void* const* d_in, const int* in_sizes, int n_in,
                              void* d_out, int out_size, void* d_ws, size_t ws_size,
                              hipStream_t stream) {
  const float* x = (const float*)d_in[0];       // [2,2048,1024]
  const float* Wqkv = (const float*)d_in[1];    // [1024,3072]
  const float* bqkv = (const float*)d_in[2];    // [3072]
  const float* Wproj = (const float*)d_in[3];   // [1024,1024]
  const float* bproj = (const float*)d_in[4];   // [1024]
  float* out = (float*)d_out;                   // [2,2048,1024] fp32

  char* ws = (char*)d_ws;
  const size_t MB = 1u << 20;
  _Float16* xh     = (_Float16*)(ws + 0 * MB);   // 4M f16 = 8MB
  _Float16* wqkvt  = (_Float16*)(ws + 8 * MB);   // [3072][1024] = 6MB
  _Float16* wprojt = (_Float16*)(ws + 14 * MB);  // [1024][1024] = 2MB
  _Float16* qh     = (_Float16*)(ws + 16 * MB);  // [B,H,T,D] = 8MB (pre-scaled)
  _Float16* kh     = (_Float16*)(ws + 24 * MB);  // [B,H,T,D] = 8MB
  _Float16* vth    = (_Float16*)(ws + 32 * MB);  // [B,H,D,T] = 8MB
  _Float16* oh     = (_Float16*)(ws + 40 * MB);  // [B,T,C]   = 8MB

  cast_f16_kernel<<<2048, 256, 0, stream>>>(x, xh, 4194304);
  transp_cast_kernel<<<dim3(48, 16), 256, 0, stream>>>(Wqkv, wqkvt, 1024, 3072);
  transp_cast_kernel<<<dim3(16, 16), 256, 0, stream>>>(Wproj, wprojt, 1024, 1024);

  gemm_f16<1><<<dim3(24, 32), 256, 0, stream>>>(xh, wqkvt, bqkv, nullptr, qh, kh, vth,
                                                4096, 3072, 1024);
  attn_kernel<<<dim3(1024), 256, 0, stream>>>(qh, kh, vth, oh);
  gemm_f16<0><<<dim3(8, 32), 256, 0, stream>>>(oh, wprojt, bproj, out, nullptr, nullptr, nullptr,
                                               4096, 1024, 1024);
}

// Round 2
// 162.676 us; speedup vs baseline: 1.8906x; 1.8906x over previous
//
#include <hip/hip_runtime.h>

typedef __attribute__((ext_vector_type(8))) _Float16 h8;
typedef __attribute__((ext_vector_type(4))) float f4;

#define QKSCALE 0.18033688011112042f  // 2^-3 * log2(e): fold softmax scale + exp2 conversion into Q

// ---------------- cast x (fp32 -> f16) ----------------
__global__ __launch_bounds__(256) void cast_f16_kernel(const float* __restrict__ in,
                                                       _Float16* __restrict__ out, int n) {
  int i = (blockIdx.x * 256 + threadIdx.x) * 8;
  if (i >= n) return;
  const float4* p = (const float4*)(in + i);
  float4 a = p[0], b = p[1];
  h8 v;
  v[0] = (_Float16)a.x; v[1] = (_Float16)a.y; v[2] = (_Float16)a.z; v[3] = (_Float16)a.w;
  v[4] = (_Float16)b.x; v[5] = (_Float16)b.y; v[6] = (_Float16)b.z; v[7] = (_Float16)b.w;
  *(h8*)(out + i) = v;
}

// ---------------- transpose-cast W [K][N] fp32 -> Wt [N][K] f16 ----------------
__global__ __launch_bounds__(256) void transp_cast_kernel(const float* __restrict__ W,
                                                          _Float16* __restrict__ Wt, int K, int N) {
  __shared__ _Float16 tile[64][72];
  int k0 = blockIdx.y * 64, n0 = blockIdx.x * 64;
  int t = threadIdx.x;
#pragma unroll
  for (int i = 0; i < 16; ++i) {
    int idx = i * 256 + t;
    int kr = idx >> 6, nc = idx & 63;
    tile[kr][nc] = (_Float16)W[(size_t)(k0 + kr) * N + n0 + nc];
  }
  __syncthreads();
#pragma unroll
  for (int i = 0; i < 2; ++i) {
    int idx = i * 256 + t;
    int nr = idx >> 3, kc = (idx & 7) * 8;
    h8 v;
#pragma unroll
    for (int j = 0; j < 8; ++j) v[j] = tile[kc + j][nr];
    *(h8*)&Wt[(size_t)(n0 + nr) * K + k0 + kc] = v;
  }
}

// ---------------- GEMM: C[M,N] = A[M,K] * Bt[N,K]^T (+bias), f16 MFMA ----------------
// MODE 0: outF fp32 row-major.  MODE 1: QKV scatter -> Q[B,H,T,D]*QKSCALE, K[B,H,T,D], V^T[B,H,D,T]
template <int MODE>
__global__ __launch_bounds__(256) void gemm_f16(const _Float16* __restrict__ A,
                                                const _Float16* __restrict__ Bt,
                                                const float* __restrict__ bias,
                                                float* __restrict__ outF,
                                                _Float16* __restrict__ oQ,
                                                _Float16* __restrict__ oK,
                                                _Float16* __restrict__ oV,
                                                int M, int N, int K) {
  __shared__ _Float16 As[128 * 64];
  __shared__ _Float16 Bs[128 * 64];
  const int m0 = blockIdx.y * 128, n0 = blockIdx.x * 128;
  const int tid = threadIdx.x;
  const int wave = tid >> 6, lane = tid & 63;
  const int wr = (wave >> 1) * 64, wc = (wave & 1) * 64;
  const int lrow = lane & 15, g = lane >> 4;
  f4 acc[4][4];
  const f4 z4 = {0.f, 0.f, 0.f, 0.f};
#pragma unroll
  for (int m = 0; m < 4; ++m)
#pragma unroll
    for (int n = 0; n < 4; ++n) acc[m][n] = z4;

  for (int k0 = 0; k0 < K; k0 += 64) {
    // stage A/B tiles [128 rows][64 k] with XOR chunk swizzle (chunk = 16B)
#pragma unroll
    for (int i = 0; i < 4; ++i) {
      int L = i * 256 + tid;
      int row = L >> 3, c = L & 7;
      int cs = (c ^ (row & 7)) * 8;
      *(h8*)&As[row * 64 + c * 8] = *(const h8*)&A[(size_t)(m0 + row) * K + k0 + cs];
      *(h8*)&Bs[row * 64 + c * 8] = *(const h8*)&Bt[(size_t)(n0 + row) * K + k0 + cs];
    }
    __syncthreads();
#pragma unroll
    for (int ss = 0; ss < 2; ++ss) {
      h8 af[4], bf[4];
#pragma unroll
      for (int m = 0; m < 4; ++m) {
        int row = wr + m * 16 + lrow;
        af[m] = *(const h8*)&As[row * 64 + (((ss * 4 + g) ^ (row & 7)) * 8)];
      }
#pragma unroll
      for (int n = 0; n < 4; ++n) {
        int row = wc + n * 16 + lrow;
        bf[n] = *(const h8*)&Bs[row * 64 + (((ss * 4 + g) ^ (row & 7)) * 8)];
      }
#pragma unroll
      for (int m = 0; m < 4; ++m)
#pragma unroll
        for (int n = 0; n < 4; ++n)
          acc[m][n] = __builtin_amdgcn_mfma_f32_16x16x32_f16(af[m], bf[n], acc[m][n], 0, 0, 0);
    }
    __syncthreads();
  }

  // epilogue; C/D layout: col = lane&15, row = (lane>>4)*4 + r  [m89]
#pragma unroll
  for (int n = 0; n < 4; ++n) {
    const int gcol = n0 + wc + n * 16 + lrow;
    const float bv = bias ? bias[gcol] : 0.f;
#pragma unroll
    for (int m = 0; m < 4; ++m) {
#pragma unroll
      for (int r = 0; r < 4; ++r) {
        const int grow = m0 + wr + m * 16 + g * 4 + r;
        float v = acc[m][n][r] + bv;
        if (MODE == 0) {
          outF[(size_t)grow * N + gcol] = v;
        } else {
          int part = gcol >> 10;
          int c1 = gcol & 1023;
          int hh = c1 >> 6, d = c1 & 63;
          int b = grow >> 11, t = grow & 2047;
          int bh = b * 16 + hh;
          if (part == 0)
            oQ[((size_t)bh * 2048 + t) * 64 + d] = (_Float16)(v * QKSCALE);
          else if (part == 1)
            oK[((size_t)bh * 2048 + t) * 64 + d] = (_Float16)v;
          else
            oV[((size_t)bh * 64 + d) * 2048 + t] = (_Float16)v;
        }
      }
    }
  }
}

// ---------------- flash attention v2: split-KV across 4 waves ----------------
// Block = 32 q-rows (2 m-tiles). All 4 waves compute the same q-rows over KV
// tiles it = wave, wave+4, ... (KV tile 64). Merge (m,l,O) via LDS at the end.
// Serial depth drops 32 -> 8; K AND V frag loads issued at top of each
// iteration so global latency overlaps QK/softmax.
__global__ __launch_bounds__(256) void attn_kernel(const _Float16* __restrict__ Qg,
                                                   const _Float16* __restrict__ Kg,
                                                   const _Float16* __restrict__ Vtg,
                                                   _Float16* __restrict__ Og) {
  __shared__ _Float16 plds[4][32][72];  // wave-private P slab
  __shared__ float obuf[4][32][65];     // per-wave partial O (unnormalized)
  __shared__ float mlds[2][4][32];      // [0]=m, [1]=l per wave per q-row

  const int idx = blockIdx.x;
  // XCD-affinity: all 64 blocks of one bh land on the same XCD (round-robin %8);
  // longest blocks (high qt2) dispatch first (LPT heuristic).
  const int bh = (idx & 7) | (((idx >> 3) & 3) << 3);
  const int qt2 = 63 - (idx >> 5);
  const int q0 = qt2 * 32;

  const int wave = threadIdx.x >> 6, lane = threadIdx.x & 63;
  const int lrow = lane & 15, g = lane >> 4;
  const int b = bh >> 4, h = bh & 15;
  const _Float16* Q = Qg + (size_t)bh * 2048 * 64;
  const _Float16* K = Kg + (size_t)bh * 2048 * 64;
  const _Float16* Vt = Vtg + (size_t)bh * 64 * 2048;

  h8 aq[2][2];
#pragma unroll
  for (int mt = 0; mt < 2; ++mt)
#pragma unroll
    for (int ss = 0; ss < 2; ++ss)
      aq[mt][ss] = *(const h8*)&Q[(q0 + mt * 16 + lrow) * 64 + ss * 32 + g * 8];

  const f4 z4 = {0.f, 0.f, 0.f, 0.f};
  f4 o[2][4];
#pragma unroll
  for (int mt = 0; mt < 2; ++mt)
#pragma unroll
    for (int dt = 0; dt < 4; ++dt) o[mt][dt] = z4;
  float mrow[2][4], lsum[2][4];
#pragma unroll
  for (int mt = 0; mt < 2; ++mt)
#pragma unroll
    for (int r = 0; r < 4; ++r) { mrow[mt][r] = -1e30f; lsum[mt][r] = 0.f; }

  _Float16(*pw)[72] = plds[wave];
  const int NT = (qt2 >> 1) + 1;  // KV tiles of 64 needed for rows [q0, q0+32)

  for (int it = wave; it < NT; it += 4) {
    const int kv0 = it * 64;
    // issue ALL K and V fragment loads up front (V overlaps QK+softmax)
    h8 kf[4][2], vf[4][2];
#pragma unroll
    for (int ct = 0; ct < 4; ++ct)
#pragma unroll
      for (int ss = 0; ss < 2; ++ss)
        kf[ct][ss] = *(const h8*)&K[(kv0 + ct * 16 + lrow) * 64 + ss * 32 + g * 8];
#pragma unroll
    for (int dt = 0; dt < 4; ++dt)
#pragma unroll
      for (int ss = 0; ss < 2; ++ss)
        vf[dt][ss] = *(const h8*)&Vt[(size_t)(dt * 16 + lrow) * 2048 + kv0 + ss * 32 + g * 8];

    f4 s[2][4];
#pragma unroll
    for (int mt = 0; mt < 2; ++mt)
#pragma unroll
      for (int ct = 0; ct < 4; ++ct) s[mt][ct] = z4;
#pragma unroll
    for (int ss = 0; ss < 2; ++ss)
#pragma unroll
      for (int mt = 0; mt < 2; ++mt)
#pragma unroll
        for (int ct = 0; ct < 4; ++ct)
          s[mt][ct] = __builtin_amdgcn_mfma_f32_16x16x32_f16(aq[mt][ss], kf[ct][ss], s[mt][ct], 0, 0, 0);

    if (it == NT - 1) {  // diagonal tile: causal mask
#pragma unroll
      for (int mt = 0; mt < 2; ++mt)
#pragma unroll
        for (int ct = 0; ct < 4; ++ct)
#pragma unroll
          for (int r = 0; r < 4; ++r)
            if (kv0 + ct * 16 + lrow > q0 + mt * 16 + g * 4 + r) s[mt][ct][r] = -1e30f;
    }

    // online softmax (exp2 domain; scale folded into Q)
#pragma unroll
    for (int mt = 0; mt < 2; ++mt)
#pragma unroll
      for (int r = 0; r < 4; ++r) {
        float pm = fmaxf(fmaxf(s[mt][0][r], s[mt][1][r]), fmaxf(s[mt][2][r], s[mt][3][r]));
        pm = fmaxf(pm, __shfl_xor(pm, 1));
        pm = fmaxf(pm, __shfl_xor(pm, 2));
        pm = fmaxf(pm, __shfl_xor(pm, 4));
        pm = fmaxf(pm, __shfl_xor(pm, 8));
        float mn = fmaxf(mrow[mt][r], pm);
        float fr = __builtin_amdgcn_exp2f(mrow[mt][r] - mn);
        mrow[mt][r] = mn;
        float ps = 0.f;
#pragma unroll
        for (int ct = 0; ct < 4; ++ct) {
          float p = __builtin_amdgcn_exp2f(s[mt][ct][r] - mn);
          s[mt][ct][r] = p;
          ps += p;
        }
        ps += __shfl_xor(ps, 1);
        ps += __shfl_xor(ps, 2);
        ps += __shfl_xor(ps, 4);
        ps += __shfl_xor(ps, 8);
        lsum[mt][r] = lsum[mt][r] * fr + ps;
#pragma unroll
        for (int dt = 0; dt < 4; ++dt) o[mt][dt][r] *= fr;
      }

    // P (C/D layout) -> LDS -> A-frag layout (wave-private, no barrier)
#pragma unroll
    for (int mt = 0; mt < 2; ++mt)
#pragma unroll
      for (int ct = 0; ct < 4; ++ct)
#pragma unroll
        for (int r = 0; r < 4; ++r)
          pw[mt * 16 + g * 4 + r][ct * 16 + lrow] = (_Float16)s[mt][ct][r];

    h8 ap[2][2];
#pragma unroll
    for (int mt = 0; mt < 2; ++mt)
#pragma unroll
      for (int ss = 0; ss < 2; ++ss)
        ap[mt][ss] = *(const h8*)&pw[mt * 16 + lrow][ss * 32 + g * 8];

#pragma unroll
    for (int ss = 0; ss < 2; ++ss)
#pragma unroll
      for (int mt = 0; mt < 2; ++mt)
#pragma unroll
        for (int dt = 0; dt < 4; ++dt)
          o[mt][dt] = __builtin_amdgcn_mfma_f32_16x16x32_f16(ap[mt][ss], vf[dt][ss], o[mt][dt], 0, 0, 0);
  }

  // ---- write per-wave partials ----
  if (lrow == 0) {
#pragma unroll
    for (int mt = 0; mt < 2; ++mt)
#pragma unroll
      for (int r = 0; r < 4; ++r) {
        mlds[0][wave][mt * 16 + g * 4 + r] = mrow[mt][r];
        mlds[1][wave][mt * 16 + g * 4 + r] = lsum[mt][r];
      }
  }
#pragma unroll
  for (int mt = 0; mt < 2; ++mt)
#pragma unroll
    for (int dt = 0; dt < 4; ++dt)
#pragma unroll
      for (int r = 0; r < 4; ++r)
        obuf[wave][mt * 16 + g * 4 + r][dt * 16 + lrow] = o[mt][dt][r];
  __syncthreads();

  // ---- merge 4 waves & write O (f16 [B,T,C]) ----
  {
    const int ql = threadIdx.x >> 3;        // 0..31
    const int d0 = (threadIdx.x & 7) * 8;   // 0..56
    float m0 = mlds[0][0][ql], m1 = mlds[0][1][ql], m2 = mlds[0][2][ql], m3 = mlds[0][3][ql];
    float M = fmaxf(fmaxf(m0, m1), fmaxf(m2, m3));
    float f0 = __builtin_amdgcn_exp2f(m0 - M);
    float f1 = __builtin_amdgcn_exp2f(m1 - M);
    float f2 = __builtin_amdgcn_exp2f(m2 - M);
    float f3 = __builtin_amdgcn_exp2f(m3 - M);
    float l = f0 * mlds[1][0][ql] + f1 * mlds[1][1][ql] + f2 * mlds[1][2][ql] + f3 * mlds[1][3][ql];
    float inv = 1.f / l;
    h8 outv;
#pragma unroll
    for (int j = 0; j < 8; ++j) {
      float v = f0 * obuf[0][ql][d0 + j] + f1 * obuf[1][ql][d0 + j] +
                f2 * obuf[2][ql][d0 + j] + f3 * obuf[3][ql][d0 + j];
      outv[j] = (_Float16)(v * inv);
    }
    *(h8*)&Og[((size_t)b * 2048 + q0 + ql) * 1024 + h * 64 + d0] = outv;
  }
}

// ---------------- launch ----------------
extern "C" void kernel_launch(void* const* d_in, const int* in_sizes, int n_in,
                              void* d_out, int out_size, void* d_ws, size_t ws_size,
                              hipStream_t stream) {
  const float* x = (const float*)d_in[0];       // [2,2048,1024]
  const float* Wqkv = (const float*)d_in[1];    // [1024,3072]
  const float* bqkv = (const float*)d_in[2];    // [3072]
  const float* Wproj = (const float*)d_in[3];   // [1024,1024]
  const float* bproj = (const float*)d_in[4];   // [1024]
  float* out = (float*)d_out;                   // [2,2048,1024] fp32

  char* ws = (char*)d_ws;
  const size_t MB = 1u << 20;
  _Float16* xh     = (_Float16*)(ws + 0 * MB);   // 4M f16 = 8MB
  _Float16* wqkvt  = (_Float16*)(ws + 8 * MB);   // [3072][1024] = 6MB
  _Float16* wprojt = (_Float16*)(ws + 14 * MB);  // [1024][1024] = 2MB
  _Float16* qh     = (_Float16*)(ws + 16 * MB);  // [B,H,T,D] = 8MB (pre-scaled)
  _Float16* kh     = (_Float16*)(ws + 24 * MB);  // [B,H,T,D] = 8MB
  _Float16* vth    = (_Float16*)(ws + 32 * MB);  // [B,H,D,T] = 8MB
  _Float16* oh     = (_Float16*)(ws + 40 * MB);  // [B,T,C]   = 8MB

  cast_f16_kernel<<<2048, 256, 0, stream>>>(x, xh, 4194304);
  transp_cast_kernel<<<dim3(48, 16), 256, 0, stream>>>(Wqkv, wqkvt, 1024, 3072);
  transp_cast_kernel<<<dim3(16, 16), 256, 0, stream>>>(Wproj, wprojt, 1024, 1024);

  gemm_f16<1><<<dim3(24, 32), 256, 0, stream>>>(xh, wqkvt, bqkv, nullptr, qh, kh, vth,
                                                4096, 3072, 1024);
  attn_kernel<<<dim3(2048), 256, 0, stream>>>(qh, kh, vth, oh);
  gemm_f16<0><<<dim3(8, 32), 256, 0, stream>>>(oh, wprojt, bproj, out, nullptr, nullptr, nullptr,
                                               4096, 1024, 1024);
}